// Round 16
// baseline (1191.761 us; speedup 1.0000x reference)
//
#include <hip/hip_runtime.h>
#include <hip/hip_bf16.h>
#include <cstdint>
#include <cstddef>

#define HIDDEN_ 4096
#define NHEAD 32
#define HDIM 128
#define SEQ 2048
#define BATCH 2
#define MROWS (BATCH * SEQ)      // 4096
#define QKVN (3 * HIDDEN_)       // 12288

typedef __bf16 bf16;
typedef __bf16 bf16x8 __attribute__((ext_vector_type(8)));
typedef float f32x4 __attribute__((ext_vector_type(4)));

#define AS1 __attribute__((address_space(1)))
#define AS3 __attribute__((address_space(3)))
#define PH_BAR do { asm volatile("" ::: "memory"); __builtin_amdgcn_s_barrier(); asm volatile("" ::: "memory"); } while (0)
#define MFMA_(d, a_, b_) (d) = __builtin_amdgcn_mfma_f32_16x16x32_bf16((a_), (b_), (d), 0, 0, 0)

// ---------------- cast fp32 -> bf16, 8 elems/thread ----------------
__global__ __launch_bounds__(256) void cast_bf16_k(const float* __restrict__ in,
                                                   bf16* __restrict__ out, int n) {
  int i = (blockIdx.x * 256 + threadIdx.x) * 8;
  if (i >= n) return;
  f32x4 a = *(const f32x4*)(in + i);
  f32x4 b = *(const f32x4*)(in + i + 4);
  bf16x8 o;
  o[0] = (bf16)a[0]; o[1] = (bf16)a[1]; o[2] = (bf16)a[2]; o[3] = (bf16)a[3];
  o[4] = (bf16)b[0]; o[5] = (bf16)b[1]; o[6] = (bf16)b[2]; o[7] = (bf16)b[3];
  *(bf16x8*)(out + i) = o;
}

// ---------------- transpose + cast v2: in[R][C] fp32 -> out[C][R] bf16 ----------------
__global__ __launch_bounds__(256) void transpose_cast_k(const float* __restrict__ in,
                                                        bf16* __restrict__ out,
                                                        int R, int C) {
  __shared__ float tile[64][65];
  const int c0 = blockIdx.x * 64, r0 = blockIdx.y * 64;
  const int tr = threadIdx.x >> 4;
  const int tc4 = (threadIdx.x & 15) * 4;
#pragma unroll
  for (int p = 0; p < 4; p++) {
    const int r = p * 16 + tr;
    f32x4 v = *(const f32x4*)&in[(size_t)(r0 + r) * C + c0 + tc4];
    tile[r][tc4 + 0] = v[0]; tile[r][tc4 + 1] = v[1];
    tile[r][tc4 + 2] = v[2]; tile[r][tc4 + 3] = v[3];
  }
  __syncthreads();
  const int oc = threadIdx.x >> 3;
  const int or8 = (threadIdx.x & 7) * 8;
#pragma unroll
  for (int p = 0; p < 2; p++) {
    const int c = p * 32 + oc;
    bf16x8 o;
#pragma unroll
    for (int j = 0; j < 8; j++) o[j] = (bf16)tile[or8 + j][c];
    *(bf16x8*)&out[(size_t)(c0 + c) * R + r0 + or8] = o;
  }
}

// ---------------- 256x256 4-phase GEMM (best measured: ~394us, 0 conflicts) ----------------
// Round-12 proven config. 512 threads = 8 waves (2M x 4N), per-wave C = 128x64,
// 16x16x32 MFMA, BK=64, 2 K-tiles/iter. LDS 128 KiB A0/A1/B0/B1 [256][64] bf16,
// XOR swizzle (byte ^= (row&7)<<4) via pre-swizzled global source + swizzled
// ds_read. 4 merged phases/iter (single barrier each), stages quarter-audited:
// A1<-tw @ph01, B0<-tu @ph23, A0<-tu @ph45, B1<-tv @ph67; vmcnt(4) at ph23/ph67.
template <int EPI>
__global__ __launch_bounds__(512, 2) void gemm256_k(
    const bf16* __restrict__ A, const bf16* __restrict__ BT,
    const float* __restrict__ bias, float* __restrict__ outF,
    bf16* __restrict__ Qb, bf16* __restrict__ Kb, bf16* __restrict__ Vt,
    int M, int N, int K, int nbx) {
  __shared__ char lds[131072];
  char* const A0 = lds;
  char* const A1 = lds + 32768;
  char* const B0 = lds + 65536;
  char* const B1 = lds + 98304;

  const int tid = threadIdx.x;
  const int w = tid >> 6, l = tid & 63;
  const int lg = l >> 4, cl = l & 15;
  const int wm = (w >> 2) * 128;
  const int wn = (w & 3) * 64;

  const int cpx = (int)gridDim.x >> 3;
  const int bid = blockIdx.x;
  const int swz = (bid & 7) * cpx + (bid >> 3);
  const int bx = swz % nbx, by = swz / nbx;
  const int m0 = by * 256, n0 = bx * 256;

  const int NT = K >> 6;
  const int NI = K >> 7;

  const bf16* gA[2][2]; const bf16* gB[2][2];
#pragma unroll
  for (int half = 0; half < 2; ++half)
#pragma unroll
    for (int i = 0; i < 2; ++i) {
      const int ci = i * 512 + tid;
      const int r = ci >> 3;
      const int cb = ((ci & 7) << 4) ^ ((r & 7) << 4);
      gA[half][i] = A + (size_t)(m0 + half * 128 + r) * K + (cb >> 1);
      gB[half][i] = BT + (size_t)(n0 + half * 128 + r) * K + (cb >> 1);
    }

  int offA[8][2], offB[4][2];
#pragma unroll
  for (int mf = 0; mf < 8; ++mf) {
    const int r = wm + mf * 16 + cl;
#pragma unroll
    for (int ks = 0; ks < 2; ++ks)
      offA[mf][ks] = r * 128 + ((ks * 64 + lg * 16) ^ ((r & 7) << 4));
  }
#pragma unroll
  for (int nf = 0; nf < 4; ++nf) {
    const int r = wn + nf * 16 + cl;
#pragma unroll
    for (int ks = 0; ks < 2; ++ks)
      offB[nf][ks] = r * 128 + ((ks * 64 + lg * 16) ^ ((r & 7) << 4));
  }

  auto stageA = [&](char* buf, int half, int kt) {
#pragma unroll
    for (int i = 0; i < 2; ++i) {
      const int ci = i * 512 + tid;
      __builtin_amdgcn_global_load_lds((const AS1 void*)(gA[half][i] + kt * 64),
                                       (AS3 void*)(buf + half * 16384 + ci * 16), 16, 0, 0);
    }
  };
  auto stageB = [&](char* buf, int half, int kt) {
#pragma unroll
    for (int i = 0; i < 2; ++i) {
      const int ci = i * 512 + tid;
      __builtin_amdgcn_global_load_lds((const AS1 void*)(gB[half][i] + kt * 64),
                                       (AS3 void*)(buf + half * 16384 + ci * 16), 16, 0, 0);
    }
  };
  auto rdA = [&](const char* buf, int mf, int ks) -> bf16x8 {
    return *(const bf16x8*)(buf + offA[mf][ks]);
  };
  auto rdB = [&](const char* buf, int nf, int ks) -> bf16x8 {
    return *(const bf16x8*)(buf + offB[nf][ks]);
  };

  f32x4 acc[8][4] = {};
  bf16x8 alo[4][2], ahi[4][2], blo[2][2], bhi[2][2];

  stageA(A0, 0, 0); stageB(B0, 0, 0); stageA(A0, 1, 0); stageB(B0, 1, 0);
  stageB(B1, 0, 1); stageB(B1, 1, 1);
  asm volatile("s_waitcnt vmcnt(4)" ::: "memory");
  PH_BAR;

  for (int j = 0; j < NI; ++j) {
    const int tw = 2 * j + 1;
    const int tu = (2 * j + 2) & (NT - 1);
    const int tv = (2 * j + 3) & (NT - 1);

    // ---- ph01: reads A0.lo + B0 all; stage A1<-tw; 32 MFMA ----
#pragma unroll
    for (int mf = 0; mf < 4; ++mf) { alo[mf][0] = rdA(A0, mf, 0); alo[mf][1] = rdA(A0, mf, 1); }
#pragma unroll
    for (int nf = 0; nf < 2; ++nf) { blo[nf][0] = rdB(B0, nf, 0); blo[nf][1] = rdB(B0, nf, 1); }
#pragma unroll
    for (int nf = 0; nf < 2; ++nf) { bhi[nf][0] = rdB(B0, 2 + nf, 0); bhi[nf][1] = rdB(B0, 2 + nf, 1); }
    stageA(A1, 0, tw);
    stageA(A1, 1, tw);
    __builtin_amdgcn_s_setprio(1);
#pragma unroll
    for (int mf = 0; mf < 4; ++mf)
#pragma unroll
      for (int nf = 0; nf < 2; ++nf)
#pragma unroll
        for (int ks = 0; ks < 2; ++ks) MFMA_(acc[mf][nf], alo[mf][ks], blo[nf][ks]);
#pragma unroll
    for (int mf = 0; mf < 4; ++mf)
#pragma unroll
      for (int nf = 0; nf < 2; ++nf)
#pragma unroll
        for (int ks = 0; ks < 2; ++ks) MFMA_(acc[mf][2 + nf], alo[mf][ks], bhi[nf][ks]);
    __builtin_amdgcn_s_setprio(0);
    PH_BAR;

    // ---- ph23: reads A0.hi; stage B0<-tu; 32 MFMA; vmcnt(4) drains tw ----
#pragma unroll
    for (int mf = 0; mf < 4; ++mf) { ahi[mf][0] = rdA(A0, 4 + mf, 0); ahi[mf][1] = rdA(A0, 4 + mf, 1); }
    stageB(B0, 0, tu);
    stageB(B0, 1, tu);
    __builtin_amdgcn_s_setprio(1);
#pragma unroll
    for (int mf = 0; mf < 4; ++mf)
#pragma unroll
      for (int nf = 0; nf < 2; ++nf)
#pragma unroll
        for (int ks = 0; ks < 2; ++ks) MFMA_(acc[4 + mf][2 + nf], ahi[mf][ks], bhi[nf][ks]);
#pragma unroll
    for (int mf = 0; mf < 4; ++mf)
#pragma unroll
      for (int nf = 0; nf < 2; ++nf)
#pragma unroll
        for (int ks = 0; ks < 2; ++ks) MFMA_(acc[4 + mf][nf], ahi[mf][ks], blo[nf][ks]);
    __builtin_amdgcn_s_setprio(0);
    asm volatile("s_waitcnt vmcnt(4)" ::: "memory");
    PH_BAR;

    // ---- ph45: reads A1.lo + B1 all; stage A0<-tu; 32 MFMA ----
#pragma unroll
    for (int mf = 0; mf < 4; ++mf) { alo[mf][0] = rdA(A1, mf, 0); alo[mf][1] = rdA(A1, mf, 1); }
#pragma unroll
    for (int nf = 0; nf < 2; ++nf) { blo[nf][0] = rdB(B1, nf, 0); blo[nf][1] = rdB(B1, nf, 1); }
#pragma unroll
    for (int nf = 0; nf < 2; ++nf) { bhi[nf][0] = rdB(B1, 2 + nf, 0); bhi[nf][1] = rdB(B1, 2 + nf, 1); }
    stageA(A0, 0, tu);
    stageA(A0, 1, tu);
    __builtin_amdgcn_s_setprio(1);
#pragma unroll
    for (int mf = 0; mf < 4; ++mf)
#pragma unroll
      for (int nf = 0; nf < 2; ++nf)
#pragma unroll
        for (int ks = 0; ks < 2; ++ks) MFMA_(acc[mf][nf], alo[mf][ks], blo[nf][ks]);
#pragma unroll
    for (int mf = 0; mf < 4; ++mf)
#pragma unroll
      for (int nf = 0; nf < 2; ++nf)
#pragma unroll
        for (int ks = 0; ks < 2; ++ks) MFMA_(acc[mf][2 + nf], alo[mf][ks], bhi[nf][ks]);
    __builtin_amdgcn_s_setprio(0);
    PH_BAR;

    // ---- ph67: reads A1.hi; stage B1<-tv; 32 MFMA; vmcnt(4) drains tu ----
#pragma unroll
    for (int mf = 0; mf < 4; ++mf) { ahi[mf][0] = rdA(A1, 4 + mf, 0); ahi[mf][1] = rdA(A1, 4 + mf, 1); }
    stageB(B1, 0, tv);
    stageB(B1, 1, tv);
    __builtin_amdgcn_s_setprio(1);
#pragma unroll
    for (int mf = 0; mf < 4; ++mf)
#pragma unroll
      for (int nf = 0; nf < 2; ++nf)
#pragma unroll
        for (int ks = 0; ks < 2; ++ks) MFMA_(acc[4 + mf][2 + nf], ahi[mf][ks], bhi[nf][ks]);
#pragma unroll
    for (int mf = 0; mf < 4; ++mf)
#pragma unroll
      for (int nf = 0; nf < 2; ++nf)
#pragma unroll
        for (int ks = 0; ks < 2; ++ks) MFMA_(acc[4 + mf][nf], ahi[mf][ks], blo[nf][ks]);
    __builtin_amdgcn_s_setprio(0);
    asm volatile("s_waitcnt vmcnt(4)" ::: "memory");
    PH_BAR;
  }

  // ---- epilogue: bias + store/scatter ----
#pragma unroll
  for (int mf = 0; mf < 8; ++mf) {
#pragma unroll
    for (int nf = 0; nf < 4; ++nf) {
      const int col = n0 + wn + nf * 16 + cl;
      const float bv = bias[col];
#pragma unroll
      for (int r = 0; r < 4; ++r) {
        const int row = m0 + wm + mf * 16 + lg * 4 + r;
        const float v = acc[mf][nf][r] + bv;
        if (EPI == 0) {
          const int which = col >> 12, rem = col & 4095;
          const int h = rem >> 7, d = rem & 127;
          const int b = row >> 11, s = row & 2047;
          const size_t bh = (size_t)b * NHEAD + h;
          if (which == 0)      Qb[(bh * SEQ + s) * HDIM + d] = (bf16)v;
          else if (which == 1) Kb[(bh * SEQ + s) * HDIM + d] = (bf16)v;
          else                 Vt[(bh * HDIM + d) * SEQ + s] = (bf16)v;
        } else {
          outF[(size_t)row * N + col] = v;
        }
      }
    }
  }
}

// ---------------- flash attention v4: V from global (no V staging), 3 blocks/CU ----------------
// 4 waves x 32 q-rows (2 m-frags share K fragments). K dbuf in LDS (swizzled,
// global_load_lds); V fragments read DIRECTLY from global Vt[d][s] — natural
// 16B-contiguous loads, no swizzle, all-wave redundant reads served by L2
// (per-XCD V working set ~4MB). P round-trip stays in LDS (16 KB).
// LDS = 2x16 (K) + 16 (P) = 48 KB -> 3 blocks/CU = 12 waves/CU (was 8).
// defer-max (T13) retained.
__global__ __launch_bounds__(256, 3) void attn_k(const bf16* __restrict__ Qb,
                                                 const bf16* __restrict__ Kb,
                                                 const bf16* __restrict__ Vt,
                                                 bf16* __restrict__ ctx) {
  __shared__ bf16 Ks[2][64 * 128];   // 2 x 16 KB
  __shared__ bf16 Pl[4][32 * 64];    // 16 KB
  const int tid = threadIdx.x, w = tid >> 6, l = tid & 63;
  const int bid = blockIdx.x;
  const int qt = 15 - (bid >> 6);          // longest blocks first
  const int bh = bid & 63;
  const int h = bh & (NHEAD - 1), b = bh >> 5;
  const int qbase = qt * 128 + w * 32;
  const int nt = 2 * qt + 2;
  const float slope = exp2f(-0.25f * (float)(h + 1));
  const float scale = 1.0f / 128.0f;
  const int lg = l >> 4, cl = l & 15;

  const bf16* Qp = Qb + (size_t)bh * SEQ * HDIM;
  const bf16* Kp = Kb + (size_t)bh * SEQ * HDIM;
  const bf16* Vp = Vt + (size_t)bh * HDIM * SEQ;
  char* plb = (char*)&Pl[w][0];

  bf16x8 qf[2][4];
#pragma unroll
  for (int mfr = 0; mfr < 2; ++mfr)
#pragma unroll
    for (int kb = 0; kb < 4; ++kb)
      qf[mfr][kb] = *(const bf16x8*)&Qp[(size_t)(qbase + mfr * 16 + cl) * HDIM + kb * 32 + lg * 8];

  float mi[2][4], li[2][4];
#pragma unroll
  for (int mfr = 0; mfr < 2; ++mfr)
#pragma unroll
    for (int r = 0; r < 4; ++r) { mi[mfr][r] = -3.0e38f; li[mfr][r] = 0.0f; }
  f32x4 oacc[2][8] = {};

  auto stageK = [&](int buf, int t) {
    const int kv0 = t * 64;
#pragma unroll
    for (int i = 0; i < 4; i++) {
      const int ci = i * 256 + tid;  // 1024 chunks of 16B = 16 KB
      const int r = ci >> 4;
      const int cbl = ((ci & 15) << 4) ^ ((r & 7) << 4);
      const bf16* src = Kp + (size_t)(kv0 + r) * HDIM + (cbl >> 1);
      __builtin_amdgcn_global_load_lds(
          (const AS1 void*)src,
          (AS3 void*)((char*)&Ks[buf][0] + ci * 16), 16, 0, 0);
    }
  };

  stageK(0, 0);
  __syncthreads();

  for (int t = 0; t < nt; ++t) {
    const int cur = t & 1;
    if (t + 1 < nt) stageK(cur ^ 1, t + 1);
    const int kv0 = t * 64;

    if (kv0 <= qbase + 31) {
      char* ksb = (char*)&Ks[cur][0];
      // ---- S = Q K^T: 16 kf LDS reads feed 32 MFMA ----
      f32x4 sacc[2][4] = {};
      __builtin_amdgcn_s_setprio(1);
#pragma unroll
      for (int nb = 0; nb < 4; nb++) {
#pragma unroll
        for (int kb = 0; kb < 4; kb++) {
          const int row = nb * 16 + cl;
          const int cb = (kb * 64 + lg * 16) ^ ((row & 7) << 4);
          bf16x8 kf = *(const bf16x8*)(ksb + row * 256 + cb);
#pragma unroll
          for (int mfr = 0; mfr < 2; ++mfr)
            sacc[mfr][nb] = __builtin_amdgcn_mfma_f32_16x16x32_bf16(qf[mfr][kb], kf, sacc[mfr][nb], 0, 0, 0);
        }
      }
      __builtin_amdgcn_s_setprio(0);
      // ---- softmax per m-frag, with defer-max ----
#pragma unroll
      for (int mfr = 0; mfr < 2; ++mfr) {
        float pm[4];
#pragma unroll
        for (int r = 0; r < 4; r++) pm[r] = -3.0e38f;
#pragma unroll
        for (int nb = 0; nb < 4; nb++) {
          const int kv = kv0 + nb * 16 + cl;
#pragma unroll
          for (int r = 0; r < 4; r++) {
            const int q = qbase + mfr * 16 + lg * 4 + r;
            float v = sacc[mfr][nb][r] * scale + slope * (float)(kv - q);
            v = (kv <= q) ? v : -3.0e38f;
            sacc[mfr][nb][r] = v;
            pm[r] = fmaxf(pm[r], v);
          }
        }
#pragma unroll
        for (int r = 0; r < 4; r++) {
          pm[r] = fmaxf(pm[r], __shfl_xor(pm[r], 1));
          pm[r] = fmaxf(pm[r], __shfl_xor(pm[r], 2));
          pm[r] = fmaxf(pm[r], __shfl_xor(pm[r], 4));
          pm[r] = fmaxf(pm[r], __shfl_xor(pm[r], 8));
        }
        int need = 0;
#pragma unroll
        for (int r = 0; r < 4; r++) need |= (pm[r] > mi[mfr][r] + 8.0f) ? 1 : 0;
        const bool resc = __any(need);
        float alpha[4];
        if (resc) {
#pragma unroll
          for (int r = 0; r < 4; r++) {
            const float nm = fmaxf(mi[mfr][r], pm[r]);
            alpha[r] = __expf(mi[mfr][r] - nm);
            mi[mfr][r] = nm;
          }
        }
        float rs[4] = {0.0f, 0.0f, 0.0f, 0.0f};
#pragma unroll
        for (int nb = 0; nb < 4; nb++) {
#pragma unroll
          for (int r = 0; r < 4; r++) {
            const float p = __expf(sacc[mfr][nb][r] - mi[mfr][r]);
            rs[r] += p;
            const int row = mfr * 16 + lg * 4 + r;
            *(bf16*)(plb + row * 128 + ((((nb * 16 + cl) << 1)) ^ ((row & 7) << 4))) = (bf16)p;
          }
        }
#pragma unroll
        for (int r = 0; r < 4; r++) {
          rs[r] += __shfl_xor(rs[r], 1);
          rs[r] += __shfl_xor(rs[r], 2);
          rs[r] += __shfl_xor(rs[r], 4);
          rs[r] += __shfl_xor(rs[r], 8);
        }
        if (resc) {
#pragma unroll
          for (int r = 0; r < 4; r++) li[mfr][r] = li[mfr][r] * alpha[r] + rs[r];
#pragma unroll
          for (int db = 0; db < 8; db++)
#pragma unroll
            for (int r = 0; r < 4; r++) oacc[mfr][db][r] *= alpha[r];
        } else {
#pragma unroll
          for (int r = 0; r < 4; r++) li[mfr][r] += rs[r];
        }
      }
      // ---- PV: P from LDS, V fragments DIRECT from global (no staging) ----
      bf16x8 pa[2][2];
#pragma unroll
      for (int mfr = 0; mfr < 2; ++mfr)
#pragma unroll
        for (int ks = 0; ks < 2; ks++) {
          const int cb = (ks * 64 + lg * 16) ^ ((cl & 7) << 4);
          pa[mfr][ks] = *(const bf16x8*)(plb + (mfr * 16 + cl) * 128 + cb);
        }
      __builtin_amdgcn_s_setprio(1);
#pragma unroll
      for (int db = 0; db < 8; db++) {
#pragma unroll
        for (int ks = 0; ks < 2; ks++) {
          bf16x8 vf = *(const bf16x8*)&Vp[(size_t)(db * 16 + cl) * SEQ + kv0 + ks * 32 + lg * 8];
#pragma unroll
          for (int mfr = 0; mfr < 2; ++mfr)
            oacc[mfr][db] = __builtin_amdgcn_mfma_f32_16x16x32_bf16(pa[mfr][ks], vf, oacc[mfr][db], 0, 0, 0);
        }
      }
      __builtin_amdgcn_s_setprio(0);
    }
    __syncthreads();
  }

#pragma unroll
  for (int mfr = 0; mfr < 2; ++mfr) {
    float inv[4];
#pragma unroll
    for (int r = 0; r < 4; r++) inv[r] = 1.0f / li[mfr][r];
#pragma unroll
    for (int db = 0; db < 8; db++) {
#pragma unroll
      for (int r = 0; r < 4; r++) {
        const int q = qbase + mfr * 16 + lg * 4 + r;
        ctx[((size_t)(b * SEQ + q)) * HIDDEN_ + h * HDIM + db * 16 + cl] = (bf16)(oacc[mfr][db][r] * inv[r]);
      }
    }
  }
}

// ---------------- launcher ----------------
extern "C" void kernel_launch(void* const* d_in, const int* in_sizes, int n_in,
                              void* d_out, int out_size, void* d_ws, size_t ws_size,
                              hipStream_t stream) {
  const float* hs     = (const float*)d_in[0];
  const float* w_attn = (const float*)d_in[1];
  const float* b_attn = (const float*)d_in[2];
  const float* w_proj = (const float*)d_in[3];
  const float* b_proj = (const float*)d_in[4];
  float* out = (float*)d_out;

  char* ws = (char*)d_ws;
  bf16* Xb  = (bf16*)(ws + 0);           // [4096][4096]        33.5 MB
  bf16* WaT = (bf16*)(ws + 33554432);    // [12288][4096]      100.7 MB
  bf16* WpT = (bf16*)(ws + 134217728);   // [4096][4096]        33.5 MB
  bf16* Qb  = (bf16*)(ws + 167772160);   // [B,H,S,D]           33.5 MB
  bf16* Kb  = (bf16*)(ws + 201326592);   // [B,H,S,D]           33.5 MB
  bf16* Vt  = (bf16*)(ws + 234881024);   // [B,H,D,S]           33.5 MB
  bf16* ctx = (bf16*)(ws + 268435456);   // [4096][4096]        33.5 MB

  cast_bf16_k<<<(MROWS * HIDDEN_) / (256 * 8), 256, 0, stream>>>(hs, Xb, MROWS * HIDDEN_);
  transpose_cast_k<<<dim3(QKVN / 64, HIDDEN_ / 64), 256, 0, stream>>>(w_attn, WaT, HIDDEN_, QKVN);
  transpose_cast_k<<<dim3(HIDDEN_ / 64, HIDDEN_ / 64), 256, 0, stream>>>(w_proj, WpT, HIDDEN_, HIDDEN_);

  gemm256_k<0><<<dim3((QKVN / 256) * (MROWS / 256)), 512, 0, stream>>>(
      Xb, WaT, b_attn, nullptr, Qb, Kb, Vt, MROWS, QKVN, HIDDEN_, QKVN / 256);

  attn_k<<<16 * 64, 256, 0, stream>>>(Qb, Kb, Vt, ctx);

  gemm256_k<1><<<dim3((HIDDEN_ / 256) * (MROWS / 256)), 512, 0, stream>>>(
      ctx, WpT, b_proj, out, nullptr, nullptr, nullptr, MROWS, HIDDEN_, HIDDEN_, HIDDEN_ / 256);
}

// Round 17
// 764.484 us; speedup vs baseline: 1.5589x; 1.5589x over previous
//
#include <hip/hip_runtime.h>
#include <hip/hip_bf16.h>
#include <cstdint>
#include <cstddef>

#define HIDDEN_ 4096
#define NHEAD 32
#define HDIM 128
#define SEQ 2048
#define BATCH 2
#define MROWS (BATCH * SEQ)      // 4096
#define QKVN (3 * HIDDEN_)       // 12288

typedef __bf16 bf16;
typedef __bf16 bf16x8 __attribute__((ext_vector_type(8)));
typedef float f32x4 __attribute__((ext_vector_type(4)));

#define AS1 __attribute__((address_space(1)))
#define AS3 __attribute__((address_space(3)))
#define PH_BAR do { asm volatile("" ::: "memory"); __builtin_amdgcn_s_barrier(); asm volatile("" ::: "memory"); } while (0)
#define MFMA_(d, a_, b_) (d) = __builtin_amdgcn_mfma_f32_16x16x32_bf16((a_), (b_), (d), 0, 0, 0)

// ---------------- cast fp32 -> bf16, 8 elems/thread ----------------
__global__ __launch_bounds__(256) void cast_bf16_k(const float* __restrict__ in,
                                                   bf16* __restrict__ out, int n) {
  int i = (blockIdx.x * 256 + threadIdx.x) * 8;
  if (i >= n) return;
  f32x4 a = *(const f32x4*)(in + i);
  f32x4 b = *(const f32x4*)(in + i + 4);
  bf16x8 o;
  o[0] = (bf16)a[0]; o[1] = (bf16)a[1]; o[2] = (bf16)a[2]; o[3] = (bf16)a[3];
  o[4] = (bf16)b[0]; o[5] = (bf16)b[1]; o[6] = (bf16)b[2]; o[7] = (bf16)b[3];
  *(bf16x8*)(out + i) = o;
}

// ---------------- transpose + cast v2: in[R][C] fp32 -> out[C][R] bf16 ----------------
__global__ __launch_bounds__(256) void transpose_cast_k(const float* __restrict__ in,
                                                        bf16* __restrict__ out,
                                                        int R, int C) {
  __shared__ float tile[64][65];
  const int c0 = blockIdx.x * 64, r0 = blockIdx.y * 64;
  const int tr = threadIdx.x >> 4;
  const int tc4 = (threadIdx.x & 15) * 4;
#pragma unroll
  for (int p = 0; p < 4; p++) {
    const int r = p * 16 + tr;
    f32x4 v = *(const f32x4*)&in[(size_t)(r0 + r) * C + c0 + tc4];
    tile[r][tc4 + 0] = v[0]; tile[r][tc4 + 1] = v[1];
    tile[r][tc4 + 2] = v[2]; tile[r][tc4 + 3] = v[3];
  }
  __syncthreads();
  const int oc = threadIdx.x >> 3;
  const int or8 = (threadIdx.x & 7) * 8;
#pragma unroll
  for (int p = 0; p < 2; p++) {
    const int c = p * 32 + oc;
    bf16x8 o;
#pragma unroll
    for (int j = 0; j < 8; j++) o[j] = (bf16)tile[or8 + j][c];
    *(bf16x8*)&out[(size_t)(c0 + c) * R + r0 + or8] = o;
  }
}

// ---------------- 256x256 4-phase GEMM (best measured: ~394us, 0 conflicts) ----------------
template <int EPI>
__global__ __launch_bounds__(512, 2) void gemm256_k(
    const bf16* __restrict__ A, const bf16* __restrict__ BT,
    const float* __restrict__ bias, float* __restrict__ outF,
    bf16* __restrict__ Qb, bf16* __restrict__ Kb, bf16* __restrict__ Vt,
    int M, int N, int K, int nbx) {
  __shared__ char lds[131072];
  char* const A0 = lds;
  char* const A1 = lds + 32768;
  char* const B0 = lds + 65536;
  char* const B1 = lds + 98304;

  const int tid = threadIdx.x;
  const int w = tid >> 6, l = tid & 63;
  const int lg = l >> 4, cl = l & 15;
  const int wm = (w >> 2) * 128;
  const int wn = (w & 3) * 64;

  const int cpx = (int)gridDim.x >> 3;
  const int bid = blockIdx.x;
  const int swz = (bid & 7) * cpx + (bid >> 3);
  const int bx = swz % nbx, by = swz / nbx;
  const int m0 = by * 256, n0 = bx * 256;

  const int NT = K >> 6;
  const int NI = K >> 7;

  const bf16* gA[2][2]; const bf16* gB[2][2];
#pragma unroll
  for (int half = 0; half < 2; ++half)
#pragma unroll
    for (int i = 0; i < 2; ++i) {
      const int ci = i * 512 + tid;
      const int r = ci >> 3;
      const int cb = ((ci & 7) << 4) ^ ((r & 7) << 4);
      gA[half][i] = A + (size_t)(m0 + half * 128 + r) * K + (cb >> 1);
      gB[half][i] = BT + (size_t)(n0 + half * 128 + r) * K + (cb >> 1);
    }

  int offA[8][2], offB[4][2];
#pragma unroll
  for (int mf = 0; mf < 8; ++mf) {
    const int r = wm + mf * 16 + cl;
#pragma unroll
    for (int ks = 0; ks < 2; ++ks)
      offA[mf][ks] = r * 128 + ((ks * 64 + lg * 16) ^ ((r & 7) << 4));
  }
#pragma unroll
  for (int nf = 0; nf < 4; ++nf) {
    const int r = wn + nf * 16 + cl;
#pragma unroll
    for (int ks = 0; ks < 2; ++ks)
      offB[nf][ks] = r * 128 + ((ks * 64 + lg * 16) ^ ((r & 7) << 4));
  }

  auto stageA = [&](char* buf, int half, int kt) {
#pragma unroll
    for (int i = 0; i < 2; ++i) {
      const int ci = i * 512 + tid;
      __builtin_amdgcn_global_load_lds((const AS1 void*)(gA[half][i] + kt * 64),
                                       (AS3 void*)(buf + half * 16384 + ci * 16), 16, 0, 0);
    }
  };
  auto stageB = [&](char* buf, int half, int kt) {
#pragma unroll
    for (int i = 0; i < 2; ++i) {
      const int ci = i * 512 + tid;
      __builtin_amdgcn_global_load_lds((const AS1 void*)(gB[half][i] + kt * 64),
                                       (AS3 void*)(buf + half * 16384 + ci * 16), 16, 0, 0);
    }
  };
  auto rdA = [&](const char* buf, int mf, int ks) -> bf16x8 {
    return *(const bf16x8*)(buf + offA[mf][ks]);
  };
  auto rdB = [&](const char* buf, int nf, int ks) -> bf16x8 {
    return *(const bf16x8*)(buf + offB[nf][ks]);
  };

  f32x4 acc[8][4] = {};
  bf16x8 alo[4][2], ahi[4][2], blo[2][2], bhi[2][2];

  stageA(A0, 0, 0); stageB(B0, 0, 0); stageA(A0, 1, 0); stageB(B0, 1, 0);
  stageB(B1, 0, 1); stageB(B1, 1, 1);
  asm volatile("s_waitcnt vmcnt(4)" ::: "memory");
  PH_BAR;

  for (int j = 0; j < NI; ++j) {
    const int tw = 2 * j + 1;
    const int tu = (2 * j + 2) & (NT - 1);
    const int tv = (2 * j + 3) & (NT - 1);

    // ---- ph01: reads A0.lo + B0 all; stage A1<-tw; 32 MFMA ----
#pragma unroll
    for (int mf = 0; mf < 4; ++mf) { alo[mf][0] = rdA(A0, mf, 0); alo[mf][1] = rdA(A0, mf, 1); }
#pragma unroll
    for (int nf = 0; nf < 2; ++nf) { blo[nf][0] = rdB(B0, nf, 0); blo[nf][1] = rdB(B0, nf, 1); }
#pragma unroll
    for (int nf = 0; nf < 2; ++nf) { bhi[nf][0] = rdB(B0, 2 + nf, 0); bhi[nf][1] = rdB(B0, 2 + nf, 1); }
    stageA(A1, 0, tw);
    stageA(A1, 1, tw);
    __builtin_amdgcn_s_setprio(1);
#pragma unroll
    for (int mf = 0; mf < 4; ++mf)
#pragma unroll
      for (int nf = 0; nf < 2; ++nf)
#pragma unroll
        for (int ks = 0; ks < 2; ++ks) MFMA_(acc[mf][nf], alo[mf][ks], blo[nf][ks]);
#pragma unroll
    for (int mf = 0; mf < 4; ++mf)
#pragma unroll
      for (int nf = 0; nf < 2; ++nf)
#pragma unroll
        for (int ks = 0; ks < 2; ++ks) MFMA_(acc[mf][2 + nf], alo[mf][ks], bhi[nf][ks]);
    __builtin_amdgcn_s_setprio(0);
    PH_BAR;

    // ---- ph23: reads A0.hi; stage B0<-tu; 32 MFMA; vmcnt(4) drains tw ----
#pragma unroll
    for (int mf = 0; mf < 4; ++mf) { ahi[mf][0] = rdA(A0, 4 + mf, 0); ahi[mf][1] = rdA(A0, 4 + mf, 1); }
    stageB(B0, 0, tu);
    stageB(B0, 1, tu);
    __builtin_amdgcn_s_setprio(1);
#pragma unroll
    for (int mf = 0; mf < 4; ++mf)
#pragma unroll
      for (int nf = 0; nf < 2; ++nf)
#pragma unroll
        for (int ks = 0; ks < 2; ++ks) MFMA_(acc[4 + mf][2 + nf], ahi[mf][ks], bhi[nf][ks]);
#pragma unroll
    for (int mf = 0; mf < 4; ++mf)
#pragma unroll
      for (int nf = 0; nf < 2; ++nf)
#pragma unroll
        for (int ks = 0; ks < 2; ++ks) MFMA_(acc[4 + mf][nf], ahi[mf][ks], blo[nf][ks]);
    __builtin_amdgcn_s_setprio(0);
    asm volatile("s_waitcnt vmcnt(4)" ::: "memory");
    PH_BAR;

    // ---- ph45: reads A1.lo + B1 all; stage A0<-tu; 32 MFMA ----
#pragma unroll
    for (int mf = 0; mf < 4; ++mf) { alo[mf][0] = rdA(A1, mf, 0); alo[mf][1] = rdA(A1, mf, 1); }
#pragma unroll
    for (int nf = 0; nf < 2; ++nf) { blo[nf][0] = rdB(B1, nf, 0); blo[nf][1] = rdB(B1, nf, 1); }
#pragma unroll
    for (int nf = 0; nf < 2; ++nf) { bhi[nf][0] = rdB(B1, 2 + nf, 0); bhi[nf][1] = rdB(B1, 2 + nf, 1); }
    stageA(A0, 0, tu);
    stageA(A0, 1, tu);
    __builtin_amdgcn_s_setprio(1);
#pragma unroll
    for (int mf = 0; mf < 4; ++mf)
#pragma unroll
      for (int nf = 0; nf < 2; ++nf)
#pragma unroll
        for (int ks = 0; ks < 2; ++ks) MFMA_(acc[mf][nf], alo[mf][ks], blo[nf][ks]);
#pragma unroll
    for (int mf = 0; mf < 4; ++mf)
#pragma unroll
      for (int nf = 0; nf < 2; ++nf)
#pragma unroll
        for (int ks = 0; ks < 2; ++ks) MFMA_(acc[mf][2 + nf], alo[mf][ks], bhi[nf][ks]);
    __builtin_amdgcn_s_setprio(0);
    PH_BAR;

    // ---- ph67: reads A1.hi; stage B1<-tv; 32 MFMA; vmcnt(4) drains tu ----
#pragma unroll
    for (int mf = 0; mf < 4; ++mf) { ahi[mf][0] = rdA(A1, 4 + mf, 0); ahi[mf][1] = rdA(A1, 4 + mf, 1); }
    stageB(B1, 0, tv);
    stageB(B1, 1, tv);
    __builtin_amdgcn_s_setprio(1);
#pragma unroll
    for (int mf = 0; mf < 4; ++mf)
#pragma unroll
      for (int nf = 0; nf < 2; ++nf)
#pragma unroll
        for (int ks = 0; ks < 2; ++ks) MFMA_(acc[4 + mf][2 + nf], ahi[mf][ks], bhi[nf][ks]);
#pragma unroll
    for (int mf = 0; mf < 4; ++mf)
#pragma unroll
      for (int nf = 0; nf < 2; ++nf)
#pragma unroll
        for (int ks = 0; ks < 2; ++ks) MFMA_(acc[4 + mf][nf], ahi[mf][ks], blo[nf][ks]);
    __builtin_amdgcn_s_setprio(0);
    asm volatile("s_waitcnt vmcnt(4)" ::: "memory");
    PH_BAR;
  }

  // ---- epilogue: bias + store/scatter ----
#pragma unroll
  for (int mf = 0; mf < 8; ++mf) {
#pragma unroll
    for (int nf = 0; nf < 4; ++nf) {
      const int col = n0 + wn + nf * 16 + cl;
      const float bv = bias[col];
#pragma unroll
      for (int r = 0; r < 4; ++r) {
        const int row = m0 + wm + mf * 16 + lg * 4 + r;
        const float v = acc[mf][nf][r] + bv;
        if (EPI == 0) {
          const int which = col >> 12, rem = col & 4095;
          const int h = rem >> 7, d = rem & 127;
          const int b = row >> 11, s = row & 2047;
          const size_t bh = (size_t)b * NHEAD + h;
          if (which == 0)      Qb[(bh * SEQ + s) * HDIM + d] = (bf16)v;
          else if (which == 1) Kb[(bh * SEQ + s) * HDIM + d] = (bf16)v;
          else                 Vt[(bh * HDIM + d) * SEQ + s] = (bf16)v;
        } else {
          outF[(size_t)row * N + col] = v;
        }
      }
    }
  }
}

// ---------------- flash attention v3 + defer-max: 4 waves x 32 q-rows ----------------
// K and V double-buffered in LDS (swizzled, global_load_lds); P per-wave LDS.
// 80 KB LDS -> 2 blocks/CU. 2 m-frags share every K/V fragment (2x MFMA/read).
__global__ __launch_bounds__(256, 2) void attn_k(const bf16* __restrict__ Qb,
                                                 const bf16* __restrict__ Kb,
                                                 const bf16* __restrict__ Vt,
                                                 bf16* __restrict__ ctx) {
  __shared__ bf16 Ks[2][64 * 128];   // 2 x 16 KB
  __shared__ bf16 Vs[2][128 * 64];   // 2 x 16 KB
  __shared__ bf16 Pl[4][32 * 64];    // 16 KB
  const int tid = threadIdx.x, w = tid >> 6, l = tid & 63;
  const int bid = blockIdx.x;
  const int qt = 15 - (bid >> 6);          // longest blocks first
  const int bh = bid & 63;
  const int h = bh & (NHEAD - 1), b = bh >> 5;
  const int qbase = qt * 128 + w * 32;
  const int nt = 2 * qt + 2;
  const float slope = exp2f(-0.25f * (float)(h + 1));
  const float scale = 1.0f / 128.0f;
  const int lg = l >> 4, cl = l & 15;

  const bf16* Qp = Qb + (size_t)bh * SEQ * HDIM;
  const bf16* Kp = Kb + (size_t)bh * SEQ * HDIM;
  const bf16* Vp = Vt + (size_t)bh * HDIM * SEQ;
  char* plb = (char*)&Pl[w][0];

  bf16x8 qf[2][4];
#pragma unroll
  for (int mfr = 0; mfr < 2; ++mfr)
#pragma unroll
    for (int kb = 0; kb < 4; ++kb)
      qf[mfr][kb] = *(const bf16x8*)&Qp[(size_t)(qbase + mfr * 16 + cl) * HDIM + kb * 32 + lg * 8];

  float mi[2][4], li[2][4];
#pragma unroll
  for (int mfr = 0; mfr < 2; ++mfr)
#pragma unroll
    for (int r = 0; r < 4; ++r) { mi[mfr][r] = -3.0e38f; li[mfr][r] = 0.0f; }
  f32x4 oacc[2][8] = {};

  auto stage = [&](int buf, int t) {
    const int kv0 = t * 64;
#pragma unroll
    for (int i = 0; i < 4; i++) {
      const int ci = i * 256 + tid;
      {  // K: 256B rows
        const int r = ci >> 4;
        const int cbl = ((ci & 15) << 4) ^ ((r & 7) << 4);
        const bf16* src = Kp + (size_t)(kv0 + r) * HDIM + (cbl >> 1);
        __builtin_amdgcn_global_load_lds(
            (const AS1 void*)src,
            (AS3 void*)((char*)&Ks[buf][0] + ci * 16), 16, 0, 0);
      }
      {  // V: 128B rows
        const int r = ci >> 3;
        const int cbl = ((ci & 7) << 4) ^ ((r & 7) << 4);
        const bf16* src = Vp + (size_t)r * SEQ + kv0 + (cbl >> 1);
        __builtin_amdgcn_global_load_lds(
            (const AS1 void*)src,
            (AS3 void*)((char*)&Vs[buf][0] + ci * 16), 16, 0, 0);
      }
    }
  };

  stage(0, 0);
  __syncthreads();

  for (int t = 0; t < nt; ++t) {
    const int cur = t & 1;
    if (t + 1 < nt) stage(cur ^ 1, t + 1);
    const int kv0 = t * 64;

    if (kv0 <= qbase + 31) {
      char* ksb = (char*)&Ks[cur][0];
      char* vsb = (char*)&Vs[cur][0];
      f32x4 sacc[2][4] = {};
      __builtin_amdgcn_s_setprio(1);
#pragma unroll
      for (int nb = 0; nb < 4; nb++) {
#pragma unroll
        for (int kb = 0; kb < 4; kb++) {
          const int row = nb * 16 + cl;
          const int cb = (kb * 64 + lg * 16) ^ ((row & 7) << 4);
          bf16x8 kf = *(const bf16x8*)(ksb + row * 256 + cb);
#pragma unroll
          for (int mfr = 0; mfr < 2; ++mfr)
            sacc[mfr][nb] = __builtin_amdgcn_mfma_f32_16x16x32_bf16(qf[mfr][kb], kf, sacc[mfr][nb], 0, 0, 0);
        }
      }
      __builtin_amdgcn_s_setprio(0);
#pragma unroll
      for (int mfr = 0; mfr < 2; ++mfr) {
        float pm[4];
#pragma unroll
        for (int r = 0; r < 4; r++) pm[r] = -3.0e38f;
#pragma unroll
        for (int nb = 0; nb < 4; nb++) {
          const int kv = kv0 + nb * 16 + cl;
#pragma unroll
          for (int r = 0; r < 4; r++) {
            const int q = qbase + mfr * 16 + lg * 4 + r;
            float v = sacc[mfr][nb][r] * scale + slope * (float)(kv - q);
            v = (kv <= q) ? v : -3.0e38f;
            sacc[mfr][nb][r] = v;
            pm[r] = fmaxf(pm[r], v);
          }
        }
#pragma unroll
        for (int r = 0; r < 4; r++) {
          pm[r] = fmaxf(pm[r], __shfl_xor(pm[r], 1));
          pm[r] = fmaxf(pm[r], __shfl_xor(pm[r], 2));
          pm[r] = fmaxf(pm[r], __shfl_xor(pm[r], 4));
          pm[r] = fmaxf(pm[r], __shfl_xor(pm[r], 8));
        }
        int need = 0;
#pragma unroll
        for (int r = 0; r < 4; r++) need |= (pm[r] > mi[mfr][r] + 8.0f) ? 1 : 0;
        const bool resc = __any(need);
        float alpha[4];
        if (resc) {
#pragma unroll
          for (int r = 0; r < 4; r++) {
            const float nm = fmaxf(mi[mfr][r], pm[r]);
            alpha[r] = __expf(mi[mfr][r] - nm);
            mi[mfr][r] = nm;
          }
        }
        float rs[4] = {0.0f, 0.0f, 0.0f, 0.0f};
#pragma unroll
        for (int nb = 0; nb < 4; nb++) {
#pragma unroll
          for (int r = 0; r < 4; r++) {
            const float p = __expf(sacc[mfr][nb][r] - mi[mfr][r]);
            rs[r] += p;
            const int row = mfr * 16 + lg * 4 + r;
            *(bf16*)(plb + row * 128 + ((((nb * 16 + cl) << 1)) ^ ((row & 7) << 4))) = (bf16)p;
          }
        }
#pragma unroll
        for (int r = 0; r < 4; r++) {
          rs[r] += __shfl_xor(rs[r], 1);
          rs[r] += __shfl_xor(rs[r], 2);
          rs[r] += __shfl_xor(rs[r], 4);
          rs[r] += __shfl_xor(rs[r], 8);
        }
        if (resc) {
#pragma unroll
          for (int r = 0; r < 4; r++) li[mfr][r] = li[mfr][r] * alpha[r] + rs[r];
#pragma unroll
          for (int db = 0; db < 8; db++)
#pragma unroll
            for (int r = 0; r < 4; r++) oacc[mfr][db][r] *= alpha[r];
        } else {
#pragma unroll
          for (int r = 0; r < 4; r++) li[mfr][r] += rs[r];
        }
      }
      bf16x8 pa[2][2];
#pragma unroll
      for (int mfr = 0; mfr < 2; ++mfr)
#pragma unroll
        for (int ks = 0; ks < 2; ks++) {
          const int cb = (ks * 64 + lg * 16) ^ ((cl & 7) << 4);
          pa[mfr][ks] = *(const bf16x8*)(plb + (mfr * 16 + cl) * 128 + cb);
        }
      __builtin_amdgcn_s_setprio(1);
#pragma unroll
      for (int db = 0; db < 8; db++) {
#pragma unroll
        for (int ks = 0; ks < 2; ks++) {
          const int row = db * 16 + cl;
          const int cb = (ks * 64 + lg * 16) ^ ((row & 7) << 4);
          bf16x8 vf = *(const bf16x8*)(vsb + row * 128 + cb);
#pragma unroll
          for (int mfr = 0; mfr < 2; ++mfr)
            oacc[mfr][db] = __builtin_amdgcn_mfma_f32_16x16x32_bf16(pa[mfr][ks], vf, oacc[mfr][db], 0, 0, 0);
        }
      }
      __builtin_amdgcn_s_setprio(0);
    }
    __syncthreads();
  }

#pragma unroll
  for (int mfr = 0; mfr < 2; ++mfr) {
    float inv[4];
#pragma unroll
    for (int r = 0; r < 4; r++) inv[r] = 1.0f / li[mfr][r];
#pragma unroll
    for (int db = 0; db < 8; db++) {
#pragma unroll
      for (int r = 0; r < 4; r++) {
        const int q = qbase + mfr * 16 + lg * 4 + r;
        ctx[((size_t)(b * SEQ + q)) * HIDDEN_ + h * HDIM + db * 16 + cl] = (bf16)(oacc[mfr][db][r] * inv[r]);
      }
    }
  }
}

// ---------------- launcher ----------------
extern "C" void kernel_launch(void* const* d_in, const int* in_sizes, int n_in,
                              void* d_out, int out_size, void* d_ws, size_t ws_size,
                              hipStream_t stream) {
  const float* hs     = (const float*)d_in[0];
  const float* w_attn = (const float*)d_in[1];
  const float* b_attn = (const float*)d_in[2];
  const float* w_proj = (const float*)d_in[3];
  const float* b_proj = (const float*)d_in[4];
  float* out = (float*)d_out;

  char* ws = (char*)d_ws;
  bf16* Xb  = (bf16*)(ws + 0);           // [4096][4096]        33.5 MB
  bf16* WaT = (bf16*)(ws + 33554432);    // [12288][4096]      100.7 MB
  bf16* WpT = (bf16*)(ws + 134217728);   // [4096][4096]        33.5 MB
  bf16* Qb  = (bf16*)(ws + 167772160);   // [B,H,S,D]           33.5 MB
  bf16* Kb  = (bf16*)(ws + 201326592);   // [B,H,S,D]           33.5 MB
  bf16* Vt  = (bf16*)(ws + 234881024);   // [B,H,D,S]           33.5 MB
  bf16* ctx = (bf16*)(ws + 268435456);   // [4096][4096]        33.5 MB

  cast_bf16_k<<<(MROWS * HIDDEN_) / (256 * 8), 256, 0, stream>>>(hs, Xb, MROWS * HIDDEN_);
  transpose_cast_k<<<dim3(QKVN / 64, HIDDEN_ / 64), 256, 0, stream>>>(w_attn, WaT, HIDDEN_, QKVN);
  transpose_cast_k<<<dim3(HIDDEN_ / 64, HIDDEN_ / 64), 256, 0, stream>>>(w_proj, WpT, HIDDEN_, HIDDEN_);

  gemm256_k<0><<<dim3((QKVN / 256) * (MROWS / 256)), 512, 0, stream>>>(
      Xb, WaT, b_attn, nullptr, Qb, Kb, Vt, MROWS, QKVN, HIDDEN_, QKVN / 256);

  attn_k<<<16 * 64, 256, 0, stream>>>(Qb, Kb, Vt, ctx);

  gemm256_k<1><<<dim3((HIDDEN_ / 256) * (MROWS / 256)), 512, 0, stream>>>(
      ctx, WpT, b_proj, out, nullptr, nullptr, nullptr, MROWS, HIDDEN_, HIDDEN_, HIDDEN_ / 256);
}